// Round 1
// baseline (8797.582 us; speedup 1.0000x reference)
//
#include <hip/hip_runtime.h>
#include <math.h>

#define NN      65536
#define KNN     12
#define WIDTH   256
#define GW      192
#define DEPTH   7
#define GLAYERS 4
#define FF      48
#define M64     (NN/64)

__device__ __forceinline__ float silu_f(float v) { return v / (1.0f + expf(-v)); }

// ---------------- prep: pack x + |x|^2 as float4 ----------------
__global__ __launch_bounds__(256) void prep_xw_kernel(const float* __restrict__ x,
                                                      float4* __restrict__ xw) {
    int i = blockIdx.x * 256 + threadIdx.x;
    float a = x[3*i], b = x[3*i+1], c = x[3*i+2];
    xw[i] = make_float4(a, b, c, a*a + b*b + c*c);
}

// ---------------- brute-force exact kNN, top-12 per thread ----------------
__global__ __launch_bounds__(256) void knn_kernel(const float4* __restrict__ xw,
                                                  int* __restrict__ knn_idx) {
    __shared__ float4 tile[1024];
    const int q = blockIdx.x * 256 + threadIdx.x;
    const float4 me = xw[q];
    const float qsq = me.w;
    float bd[KNN]; int bi[KNN];
#pragma unroll
    for (int k = 0; k < KNN; ++k) { bd[k] = 3e38f; bi[k] = -1; }

    for (int t0 = 0; t0 < NN; t0 += 1024) {
#pragma unroll
        for (int u = 0; u < 4; ++u)
            tile[u*256 + threadIdx.x] = xw[t0 + u*256 + threadIdx.x];
        __syncthreads();
        float worst = bd[KNN-1];
#pragma unroll 4
        for (int j = 0; j < 1024; ++j) {
            float4 c = tile[j];
            float dot = me.x*c.x + me.y*c.y + me.z*c.z;
            float d = fmaf(-2.0f, dot, qsq + c.w);   // x_i^2 + x_j^2 - 2 dot
            if (d < worst) {
                int gj = t0 + j;
                if (gj != q) {                        // self gets +1e9 in ref -> never selected
                    d = fmaxf(d, 0.0f);               // ref clips at 0
                    bd[KNN-1] = d; bi[KNN-1] = gj;
#pragma unroll
                    for (int k = KNN-1; k > 0; --k) { // bubble up (strict <: ties keep earlier idx)
                        if (bd[k] < bd[k-1]) {
                            float td = bd[k]; bd[k] = bd[k-1]; bd[k-1] = td;
                            int   ti = bi[k]; bi[k] = bi[k-1]; bi[k-1] = ti;
                        }
                    }
                    worst = bd[KNN-1];
                }
            }
        }
        __syncthreads();
    }
#pragma unroll
    for (int k = 0; k < KNN; ++k) knn_idx[q*KNN + k] = bi[k];
}

// ---------------- fourier features + both input layers ----------------
__global__ __launch_bounds__(256) void fourier_input_kernel(
    const float* __restrict__ x, const float* __restrict__ Bf,
    const float* __restrict__ W_in, const float* __restrict__ b_in,
    const float* __restrict__ Wg_in, const float* __restrict__ bg_in,
    float* __restrict__ h0, float* __restrict__ g0) {
    const int n = blockIdx.x * 256 + threadIdx.x;
    const float x0 = x[3*n], x1 = x[3*n+1], x2 = x[3*n+2];
    float ff[FF];
#pragma unroll
    for (int sm = 0; sm < 24; ++sm) {
        int s = sm >> 3, m = sm & 7;
        float p = x0*Bf[s*24 + m] + x1*Bf[s*24 + 8 + m] + x2*Bf[s*24 + 16 + m];
        float sv, cv; sincosf(p, &sv, &cv);
        ff[sm] = sv; ff[24 + sm] = cv;
    }
    {   // h0 = silu(ff @ W_in + b_in)
        const float4* W4 = (const float4*)W_in;
        const float4* b4 = (const float4*)b_in;
#pragma unroll 2
        for (int j4 = 0; j4 < WIDTH/4; ++j4) {
            float4 acc = b4[j4];
#pragma unroll
            for (int k = 0; k < FF; ++k) {
                float4 w = W4[k*(WIDTH/4) + j4]; float f = ff[k];
                acc.x = fmaf(f, w.x, acc.x); acc.y = fmaf(f, w.y, acc.y);
                acc.z = fmaf(f, w.z, acc.z); acc.w = fmaf(f, w.w, acc.w);
            }
            acc.x = silu_f(acc.x); acc.y = silu_f(acc.y);
            acc.z = silu_f(acc.z); acc.w = silu_f(acc.w);
            *(float4*)&h0[(size_t)n*WIDTH + j4*4] = acc;
        }
    }
    {   // g0 = silu(ff @ Wg_in + bg_in)
        const float4* W4 = (const float4*)Wg_in;
        const float4* b4 = (const float4*)bg_in;
#pragma unroll 2
        for (int j4 = 0; j4 < GW/4; ++j4) {
            float4 acc = b4[j4];
#pragma unroll
            for (int k = 0; k < FF; ++k) {
                float4 w = W4[k*(GW/4) + j4]; float f = ff[k];
                acc.x = fmaf(f, w.x, acc.x); acc.y = fmaf(f, w.y, acc.y);
                acc.z = fmaf(f, w.z, acc.z); acc.w = fmaf(f, w.w, acc.w);
            }
            acc.x = silu_f(acc.x); acc.y = silu_f(acc.y);
            acc.z = silu_f(acc.z); acc.w = silu_f(acc.w);
            *(float4*)&g0[(size_t)n*GW + j4*4] = acc;
        }
    }
}

// ---------------- gather + mean over 12 neighbors ----------------
__global__ __launch_bounds__(192) void gather_mean_kernel(const float* __restrict__ g,
                                                          const int* __restrict__ idx,
                                                          float* __restrict__ agg) {
    __shared__ int nb[KNN];
    const int n = blockIdx.x;
    if (threadIdx.x < KNN) nb[threadIdx.x] = idx[n*KNN + threadIdx.x];
    __syncthreads();
    float acc = 0.0f;
#pragma unroll
    for (int k = 0; k < KNN; ++k) acc += g[(size_t)nb[k]*GW + threadIdx.x];
    agg[(size_t)n*GW + threadIdx.x] = acc * (1.0f/12.0f);
}

// ---------------- FiLM params: (1+gamma), beta per trunk layer ----------------
__global__ __launch_bounds__(256) void film_kernel(const float* __restrict__ cond,
                                                   const float* __restrict__ Wf_g,
                                                   const float* __restrict__ bf_g,
                                                   const float* __restrict__ Wf_b,
                                                   const float* __restrict__ bf_b,
                                                   float* __restrict__ film) {
    const int l = blockIdx.x, j = threadIdx.x;
    float g = bf_g[l*WIDTH + j], b = bf_b[l*WIDTH + j];
    for (int c = 0; c < 64; ++c) {
        float cv = cond[c];
        g = fmaf(cv, Wf_g[(size_t)(l*64 + c)*WIDTH + j], g);
        b = fmaf(cv, Wf_b[(size_t)(l*64 + c)*WIDTH + j], b);
    }
    film[l*2*WIDTH + j]         = 1.0f + g;
    film[l*2*WIDTH + WIDTH + j] = b;
}

// ---------------- generic fp32 tiled GEMM, BM=BN=64, KC=32 ----------------
// EPI: 0 = silu(acc + bias)                         (graph layer, concat A/B)
//      1 = silu((acc + bias)*film_g + film_b) [+h0] (trunk FiLM)
//      2 = acc + h0                                 (graph->trunk inject)
template<int EPI>
__global__ __launch_bounds__(256) void gemm64(
    const float* __restrict__ A1, const float* __restrict__ A2,
    const float* __restrict__ B1, const float* __restrict__ B2,
    int K1, int K2, int NC,
    const float* __restrict__ bias, const float* __restrict__ film,
    const float* __restrict__ h0, float* __restrict__ C, int addSkip) {
    __shared__ float As[32][68];   // A transposed [k][m], stride 68 -> 16B-aligned rows, 2-way banks
    __shared__ float Bs[32][64];
    const int tid = threadIdx.x;
    const int bm = blockIdx.x * 64;
    const int bn = blockIdx.y * 64;
    const int tx = tid & 15, ty = tid >> 4;
    float acc[4][4] = {};
    const int Ktot = K1 + K2;

    for (int kc = 0; kc < Ktot; kc += 32) {
        const float* Asrc; const float* Bsrc; int kl, ldA;
        if (kc < K1) { Asrc = A1; Bsrc = B1; kl = kc;      ldA = K1; }
        else         { Asrc = A2; Bsrc = B2; kl = kc - K1; ldA = K2; }
#pragma unroll
        for (int u = 0; u < 2; ++u) {           // A tile: 64 rows x 32 k
            int lin = tid + u*256;
            int row = lin >> 3, k4 = (lin & 7) << 2;
            float4 v = *(const float4*)&Asrc[(size_t)(bm + row)*ldA + kl + k4];
            As[k4+0][row] = v.x; As[k4+1][row] = v.y;
            As[k4+2][row] = v.z; As[k4+3][row] = v.w;
        }
#pragma unroll
        for (int u = 0; u < 2; ++u) {           // B tile: 32 k x 64 n
            int lin = tid + u*256;
            int krow = lin >> 4, n4 = (lin & 15) << 2;
            *(float4*)&Bs[krow][n4] = *(const float4*)&Bsrc[(size_t)(kl + krow)*NC + bn + n4];
        }
        __syncthreads();
#pragma unroll
        for (int kk = 0; kk < 32; ++kk) {
            float4 a = *(const float4*)&As[kk][ty << 2];
            float4 b = *(const float4*)&Bs[kk][tx << 2];
            acc[0][0] = fmaf(a.x, b.x, acc[0][0]); acc[0][1] = fmaf(a.x, b.y, acc[0][1]);
            acc[0][2] = fmaf(a.x, b.z, acc[0][2]); acc[0][3] = fmaf(a.x, b.w, acc[0][3]);
            acc[1][0] = fmaf(a.y, b.x, acc[1][0]); acc[1][1] = fmaf(a.y, b.y, acc[1][1]);
            acc[1][2] = fmaf(a.y, b.z, acc[1][2]); acc[1][3] = fmaf(a.y, b.w, acc[1][3]);
            acc[2][0] = fmaf(a.z, b.x, acc[2][0]); acc[2][1] = fmaf(a.z, b.y, acc[2][1]);
            acc[2][2] = fmaf(a.z, b.z, acc[2][2]); acc[2][3] = fmaf(a.z, b.w, acc[2][3]);
            acc[3][0] = fmaf(a.w, b.x, acc[3][0]); acc[3][1] = fmaf(a.w, b.y, acc[3][1]);
            acc[3][2] = fmaf(a.w, b.z, acc[3][2]); acc[3][3] = fmaf(a.w, b.w, acc[3][3]);
        }
        __syncthreads();
    }

#pragma unroll
    for (int i = 0; i < 4; ++i) {
        int r = bm + (ty << 2) + i;
        float4 o;
#pragma unroll
        for (int j = 0; j < 4; ++j) {
            int c = bn + (tx << 2) + j;
            float v = acc[i][j];
            if (EPI == 0) {
                v = silu_f(v + bias[c]);
            } else if (EPI == 1) {
                v = fmaf(v + bias[c], film[c], film[NC + c]);
                v = silu_f(v);
                if (addSkip) v += h0[(size_t)r*NC + c];
            } else {
                v = v + h0[(size_t)r*NC + c];
            }
            ((float*)&o)[j] = v;
        }
        *(float4*)&C[(size_t)r*NC + bn + (tx << 2)] = o;
    }
}

// ---------------- output head: (h @ W_out + b_out) * 0.01 ----------------
__global__ __launch_bounds__(256) void out_kernel(const float* __restrict__ h,
                                                  const float* __restrict__ W_out,
                                                  const float* __restrict__ b_out,
                                                  float* __restrict__ out) {
    const int n = blockIdx.x * 256 + threadIdx.x;
    float a0 = 0.f, a1 = 0.f, a2 = 0.f;
    const float4* h4 = (const float4*)(h + (size_t)n*WIDTH);
#pragma unroll 4
    for (int k4 = 0; k4 < WIDTH/4; ++k4) {
        float4 v = h4[k4]; int k = k4*4;
        a0 = fmaf(v.x, W_out[(k+0)*3+0], a0); a1 = fmaf(v.x, W_out[(k+0)*3+1], a1); a2 = fmaf(v.x, W_out[(k+0)*3+2], a2);
        a0 = fmaf(v.y, W_out[(k+1)*3+0], a0); a1 = fmaf(v.y, W_out[(k+1)*3+1], a1); a2 = fmaf(v.y, W_out[(k+1)*3+2], a2);
        a0 = fmaf(v.z, W_out[(k+2)*3+0], a0); a1 = fmaf(v.z, W_out[(k+2)*3+1], a1); a2 = fmaf(v.z, W_out[(k+2)*3+2], a2);
        a0 = fmaf(v.w, W_out[(k+3)*3+0], a0); a1 = fmaf(v.w, W_out[(k+3)*3+1], a1); a2 = fmaf(v.w, W_out[(k+3)*3+2], a2);
    }
    out[n*3+0] = (a0 + b_out[0]) * 0.01f;
    out[n*3+1] = (a1 + b_out[1]) * 0.01f;
    out[n*3+2] = (a2 + b_out[2]) * 0.01f;
}

extern "C" void kernel_launch(void* const* d_in, const int* in_sizes, int n_in,
                              void* d_out, int out_size, void* d_ws, size_t ws_size,
                              hipStream_t stream) {
    const float* x      = (const float*)d_in[0];
    const float* cond   = (const float*)d_in[1];
    const float* Bf     = (const float*)d_in[2];
    const float* W_in   = (const float*)d_in[3];
    const float* b_in   = (const float*)d_in[4];
    const float* Wg_in  = (const float*)d_in[5];
    const float* bg_in  = (const float*)d_in[6];
    const float* Ws     = (const float*)d_in[7];
    const float* Wn     = (const float*)d_in[8];
    const float* bg     = (const float*)d_in[9];
    const float* Wg_out = (const float*)d_in[10];
    const float* W      = (const float*)d_in[11];
    const float* bmlp   = (const float*)d_in[12];
    const float* Wf_g   = (const float*)d_in[13];
    const float* bf_g   = (const float*)d_in[14];
    const float* Wf_b   = (const float*)d_in[15];
    const float* bf_b   = (const float*)d_in[16];
    const float* W_out  = (const float*)d_in[17];
    const float* b_out  = (const float*)d_in[18];
    float* out = (float*)d_out;

    // workspace layout (bytes); trunk ping-pong overlays dead graph buffers.
    char* ws = (char*)d_ws;
    int*    knn_idx = (int*)   (ws + 0);          //  3,145,728
    float4* xw      = (float4*)(ws + 3145728);    //  1,048,576
    float*  film    = (float*) (ws + 4194304);    //     14,336
    float*  h0      = (float*) (ws + 4456448);    // 67,108,864
    float*  g_a     = (float*) (ws + 71565312);   // 50,331,648
    float*  g_b     = (float*) (ws + 121896960);  // 50,331,648
    float*  agg     = (float*) (ws + 172228608);  // 50,331,648 (ends 222,560,256)
    float*  hA      = (float*) (ws + 121896960);  // overlays g_b+agg (dead at inject)
    float*  hB      = (float*) (ws + 189005824);  // ends 256,114,688  (needs ws >= ~245 MiB)

    prep_xw_kernel<<<NN/256, 256, 0, stream>>>(x, xw);
    knn_kernel<<<NN/256, 256, 0, stream>>>(xw, knn_idx);
    film_kernel<<<DEPTH, 256, 0, stream>>>(cond, Wf_g, bf_g, Wf_b, bf_b, film);
    fourier_input_kernel<<<NN/256, 256, 0, stream>>>(x, Bf, W_in, b_in, Wg_in, bg_in, h0, g_a);

    float* gin = g_a; float* gout = g_b;
    for (int l = 0; l < GLAYERS; ++l) {
        gather_mean_kernel<<<NN, GW, 0, stream>>>(gin, knn_idx, agg);
        gemm64<0><<<dim3(M64, GW/64), 256, 0, stream>>>(
            gin, agg, Ws + (size_t)l*GW*GW, Wn + (size_t)l*GW*GW,
            GW, GW, GW, bg + l*GW, nullptr, nullptr, gout, 0);
        float* t = gin; gin = gout; gout = t;
    }
    // gin == g_a here (4 swaps). inject: hA = h0 + gin @ Wg_out
    gemm64<2><<<dim3(M64, WIDTH/64), 256, 0, stream>>>(
        gin, nullptr, Wg_out, nullptr, GW, 0, WIDTH, nullptr, nullptr, h0, hA, 0);

    float* hin = hA; float* hout = hB;
    for (int l = 0; l < DEPTH; ++l) {
        int skip = (l == 2 || l == 5) ? 1 : 0;   // SKIPS = (3,6): after layers idx 2 and 5
        gemm64<1><<<dim3(M64, WIDTH/64), 256, 0, stream>>>(
            hin, nullptr, W + (size_t)l*WIDTH*WIDTH, nullptr,
            WIDTH, 0, WIDTH, bmlp + l*WIDTH, film + l*2*WIDTH, h0, hout, skip);
        float* t = hin; hin = hout; hout = t;
    }
    out_kernel<<<NN/256, 256, 0, stream>>>(hin, W_out, b_out, out);
}

// Round 2
// 4255.547 us; speedup vs baseline: 2.0673x; 2.0673x over previous
//
#include <hip/hip_runtime.h>
#include <math.h>

#define NN      65536
#define KNN     12
#define WIDTH   256
#define GW      192
#define DEPTH   7
#define GLAYERS 4
#define FF      48
#define M64     (NN/64)

#define KSEG    4            // knn split-K segments
#define SEGLEN  (NN/KSEG)    // 16384 candidates per segment
#define TILE    512          // LDS candidate tile (float4) = 8 KB
#define QCAP    16           // per-lane deferral queue capacity (32 KB)
#define QTRIG   8            // flush when any lane count >= QTRIG (batch adds <=8)

__device__ __forceinline__ float silu_f(float v) { return v / (1.0f + expf(-v)); }

// ---------------- prep: pack x + |x|^2 as float4 ----------------
__global__ __launch_bounds__(256) void prep_xw_kernel(const float* __restrict__ x,
                                                      float4* __restrict__ xw) {
    int i = blockIdx.x * 256 + threadIdx.x;
    float a = x[3*i], b = x[3*i+1], c = x[3*i+2];
    xw[i] = make_float4(a, b, c, a*a + b*b + c*c);
}

// ---------------- kNN split-K scan with per-lane LDS deferral queue ----------------
// Ladder runs only at flush: total ladder count ~ max-per-lane accepts, not wave-union.
__device__ __forceinline__ void knn_flush(float2* qbuf, int tid, int& cnt,
                                          float bd[KNN], int bi[KNN], float& worst) {
    int p = 0;
    while (__any(p < cnt)) {
        if (p < cnt) {
            float2 e = qbuf[p*256 + tid];      // [slot][tid] layout: <=4-way banks
            float d = e.x;
            if (d < bd[KNN-1]) {
                bd[KNN-1] = d; bi[KNN-1] = __float_as_int(e.y);
#pragma unroll
                for (int k = KNN-1; k > 0; --k) {
                    if (bd[k] < bd[k-1]) {
                        float td = bd[k]; bd[k] = bd[k-1]; bd[k-1] = td;
                        int   ti = bi[k]; bi[k] = bi[k-1]; bi[k-1] = ti;
                    }
                }
            }
        }
        ++p;
    }
    cnt = 0;
    worst = bd[KNN-1];
}

__global__ __launch_bounds__(256) void knn_part_kernel(const float4* __restrict__ xw,
                                                       float* __restrict__ pd,
                                                       int* __restrict__ pi) {
    __shared__ float4 tile[TILE];          //  8 KB
    __shared__ float2 qbuf[QCAP*256];      // 32 KB -> 40 KB total = 4 blocks/CU
    const int tid = threadIdx.x;
    const int q   = blockIdx.x * 256 + tid;
    const int seg = blockIdx.y;
    const float4 me = xw[q];
    const float qsq = me.w;
    float bd[KNN]; int bi[KNN];
#pragma unroll
    for (int k = 0; k < KNN; ++k) { bd[k] = 3e38f; bi[k] = -1; }
    float worst = 3e38f;
    int cnt = 0;

    for (int t0 = seg*SEGLEN; t0 < (seg+1)*SEGLEN; t0 += TILE) {
        __syncthreads();
        tile[tid]       = xw[t0 + tid];
        tile[tid + 256] = xw[t0 + 256 + tid];
        __syncthreads();
        for (int b = 0; b < TILE; b += 8) {
            if (__any(cnt >= QTRIG)) knn_flush(qbuf, tid, cnt, bd, bi, worst);
            float d[8];
#pragma unroll
            for (int u = 0; u < 8; ++u) {   // uniform address -> LDS broadcast reads
                float4 c = tile[b + u];
                float dot = me.x*c.x + me.y*c.y + me.z*c.z;
                d[u] = fmaf(-2.0f, dot, qsq + c.w);   // same formula as ref selection
            }
            float m01 = fminf(d[0],d[1]), m23 = fminf(d[2],d[3]);
            float m45 = fminf(d[4],d[5]), m67 = fminf(d[6],d[7]);
            float mn = fminf(fminf(m01,m23), fminf(m45,m67));
            if (mn < worst) {               // steady state: skip whole batch
#pragma unroll
                for (int u = 0; u < 8; ++u) {
                    if (d[u] < worst) {
                        int gj = t0 + b + u;
                        if (gj != q) {      // self excluded (ref adds +1e9)
                            float dc = fmaxf(d[u], 0.0f);   // ref clips at 0
                            qbuf[cnt*256 + tid] = make_float2(dc, __int_as_float(gj));
                            ++cnt;
                        }
                    }
                }
            }
        }
    }
    knn_flush(qbuf, tid, cnt, bd, bi, worst);
#pragma unroll
    for (int k = 0; k < KNN; ++k) {
        pd[(q*KSEG + seg)*KNN + k] = bd[k];
        pi[(q*KSEG + seg)*KNN + k] = bi[k];
    }
}

__global__ __launch_bounds__(256) void knn_merge_kernel(const float* __restrict__ pd,
                                                        const int* __restrict__ pi,
                                                        int* __restrict__ knn_idx) {
    const int q = blockIdx.x * 256 + threadIdx.x;
    float bd[KNN]; int bi[KNN];
#pragma unroll
    for (int k = 0; k < KNN; ++k) { bd[k] = pd[q*KSEG*KNN + k]; bi[k] = pi[q*KSEG*KNN + k]; }
#pragma unroll
    for (int s = 1; s < KSEG; ++s) {
        for (int k = 0; k < KNN; ++k) {
            float d = pd[(q*KSEG + s)*KNN + k];
            if (d >= bd[KNN-1]) break;      // segment lists are sorted ascending
            int gi = pi[(q*KSEG + s)*KNN + k];
            bd[KNN-1] = d; bi[KNN-1] = gi;
#pragma unroll
            for (int t = KNN-1; t > 0; --t) {
                if (bd[t] < bd[t-1]) {
                    float td = bd[t]; bd[t] = bd[t-1]; bd[t-1] = td;
                    int   ti = bi[t]; bi[t] = bi[t-1]; bi[t-1] = ti;
                }
            }
        }
    }
#pragma unroll
    for (int k = 0; k < KNN; ++k) knn_idx[q*KNN + k] = bi[k];
}

// ---------------- fourier features + both input layers ----------------
__global__ __launch_bounds__(256) void fourier_input_kernel(
    const float* __restrict__ x, const float* __restrict__ Bf,
    const float* __restrict__ W_in, const float* __restrict__ b_in,
    const float* __restrict__ Wg_in, const float* __restrict__ bg_in,
    float* __restrict__ h0, float* __restrict__ g0) {
    const int n = blockIdx.x * 256 + threadIdx.x;
    const float x0 = x[3*n], x1 = x[3*n+1], x2 = x[3*n+2];
    float ff[FF];
#pragma unroll
    for (int sm = 0; sm < 24; ++sm) {
        int s = sm >> 3, m = sm & 7;
        float p = x0*Bf[s*24 + m] + x1*Bf[s*24 + 8 + m] + x2*Bf[s*24 + 16 + m];
        float sv, cv; sincosf(p, &sv, &cv);
        ff[sm] = sv; ff[24 + sm] = cv;
    }
    {
        const float4* W4 = (const float4*)W_in;
        const float4* b4 = (const float4*)b_in;
#pragma unroll 2
        for (int j4 = 0; j4 < WIDTH/4; ++j4) {
            float4 acc = b4[j4];
#pragma unroll
            for (int k = 0; k < FF; ++k) {
                float4 w = W4[k*(WIDTH/4) + j4]; float f = ff[k];
                acc.x = fmaf(f, w.x, acc.x); acc.y = fmaf(f, w.y, acc.y);
                acc.z = fmaf(f, w.z, acc.z); acc.w = fmaf(f, w.w, acc.w);
            }
            acc.x = silu_f(acc.x); acc.y = silu_f(acc.y);
            acc.z = silu_f(acc.z); acc.w = silu_f(acc.w);
            *(float4*)&h0[(size_t)n*WIDTH + j4*4] = acc;
        }
    }
    {
        const float4* W4 = (const float4*)Wg_in;
        const float4* b4 = (const float4*)bg_in;
#pragma unroll 2
        for (int j4 = 0; j4 < GW/4; ++j4) {
            float4 acc = b4[j4];
#pragma unroll
            for (int k = 0; k < FF; ++k) {
                float4 w = W4[k*(GW/4) + j4]; float f = ff[k];
                acc.x = fmaf(f, w.x, acc.x); acc.y = fmaf(f, w.y, acc.y);
                acc.z = fmaf(f, w.z, acc.z); acc.w = fmaf(f, w.w, acc.w);
            }
            acc.x = silu_f(acc.x); acc.y = silu_f(acc.y);
            acc.z = silu_f(acc.z); acc.w = silu_f(acc.w);
            *(float4*)&g0[(size_t)n*GW + j4*4] = acc;
        }
    }
}

// ---------------- gather + mean over 12 neighbors ----------------
__global__ __launch_bounds__(192) void gather_mean_kernel(const float* __restrict__ g,
                                                          const int* __restrict__ idx,
                                                          float* __restrict__ agg) {
    __shared__ int nb[KNN];
    const int n = blockIdx.x;
    if (threadIdx.x < KNN) nb[threadIdx.x] = idx[n*KNN + threadIdx.x];
    __syncthreads();
    float acc = 0.0f;
#pragma unroll
    for (int k = 0; k < KNN; ++k) acc += g[(size_t)nb[k]*GW + threadIdx.x];
    agg[(size_t)n*GW + threadIdx.x] = acc * (1.0f/12.0f);
}

// ---------------- FiLM params ----------------
__global__ __launch_bounds__(256) void film_kernel(const float* __restrict__ cond,
                                                   const float* __restrict__ Wf_g,
                                                   const float* __restrict__ bf_g,
                                                   const float* __restrict__ Wf_b,
                                                   const float* __restrict__ bf_b,
                                                   float* __restrict__ film) {
    const int l = blockIdx.x, j = threadIdx.x;
    float g = bf_g[l*WIDTH + j], b = bf_b[l*WIDTH + j];
    for (int c = 0; c < 64; ++c) {
        float cv = cond[c];
        g = fmaf(cv, Wf_g[(size_t)(l*64 + c)*WIDTH + j], g);
        b = fmaf(cv, Wf_b[(size_t)(l*64 + c)*WIDTH + j], b);
    }
    film[l*2*WIDTH + j]         = 1.0f + g;
    film[l*2*WIDTH + WIDTH + j] = b;
}

// ---------------- generic fp32 tiled GEMM, BM=BN=64, KC=32 ----------------
template<int EPI>
__global__ __launch_bounds__(256) void gemm64(
    const float* __restrict__ A1, const float* __restrict__ A2,
    const float* __restrict__ B1, const float* __restrict__ B2,
    int K1, int K2, int NC,
    const float* __restrict__ bias, const float* __restrict__ film,
    const float* __restrict__ h0, float* __restrict__ C, int addSkip) {
    __shared__ float As[32][68];
    __shared__ float Bs[32][64];
    const int tid = threadIdx.x;
    const int bm = blockIdx.x * 64;
    const int bn = blockIdx.y * 64;
    const int tx = tid & 15, ty = tid >> 4;
    float acc[4][4] = {};
    const int Ktot = K1 + K2;

    for (int kc = 0; kc < Ktot; kc += 32) {
        const float* Asrc; const float* Bsrc; int kl, ldA;
        if (kc < K1) { Asrc = A1; Bsrc = B1; kl = kc;      ldA = K1; }
        else         { Asrc = A2; Bsrc = B2; kl = kc - K1; ldA = K2; }
#pragma unroll
        for (int u = 0; u < 2; ++u) {
            int lin = tid + u*256;
            int row = lin >> 3, k4 = (lin & 7) << 2;
            float4 v = *(const float4*)&Asrc[(size_t)(bm + row)*ldA + kl + k4];
            As[k4+0][row] = v.x; As[k4+1][row] = v.y;
            As[k4+2][row] = v.z; As[k4+3][row] = v.w;
        }
#pragma unroll
        for (int u = 0; u < 2; ++u) {
            int lin = tid + u*256;
            int krow = lin >> 4, n4 = (lin & 15) << 2;
            *(float4*)&Bs[krow][n4] = *(const float4*)&Bsrc[(size_t)(kl + krow)*NC + bn + n4];
        }
        __syncthreads();
#pragma unroll
        for (int kk = 0; kk < 32; ++kk) {
            float4 a = *(const float4*)&As[kk][ty << 2];
            float4 b = *(const float4*)&Bs[kk][tx << 2];
            acc[0][0] = fmaf(a.x, b.x, acc[0][0]); acc[0][1] = fmaf(a.x, b.y, acc[0][1]);
            acc[0][2] = fmaf(a.x, b.z, acc[0][2]); acc[0][3] = fmaf(a.x, b.w, acc[0][3]);
            acc[1][0] = fmaf(a.y, b.x, acc[1][0]); acc[1][1] = fmaf(a.y, b.y, acc[1][1]);
            acc[1][2] = fmaf(a.y, b.z, acc[1][2]); acc[1][3] = fmaf(a.y, b.w, acc[1][3]);
            acc[2][0] = fmaf(a.z, b.x, acc[2][0]); acc[2][1] = fmaf(a.z, b.y, acc[2][1]);
            acc[2][2] = fmaf(a.z, b.z, acc[2][2]); acc[2][3] = fmaf(a.z, b.w, acc[2][3]);
            acc[3][0] = fmaf(a.w, b.x, acc[3][0]); acc[3][1] = fmaf(a.w, b.y, acc[3][1]);
            acc[3][2] = fmaf(a.w, b.z, acc[3][2]); acc[3][3] = fmaf(a.w, b.w, acc[3][3]);
        }
        __syncthreads();
    }

#pragma unroll
    for (int i = 0; i < 4; ++i) {
        int r = bm + (ty << 2) + i;
        float4 o;
#pragma unroll
        for (int j = 0; j < 4; ++j) {
            int c = bn + (tx << 2) + j;
            float v = acc[i][j];
            if (EPI == 0) {
                v = silu_f(v + bias[c]);
            } else if (EPI == 1) {
                v = fmaf(v + bias[c], film[c], film[NC + c]);
                v = silu_f(v);
                if (addSkip) v += h0[(size_t)r*NC + c];
            } else {
                v = v + h0[(size_t)r*NC + c];
            }
            ((float*)&o)[j] = v;
        }
        *(float4*)&C[(size_t)r*NC + bn + (tx << 2)] = o;
    }
}

// ---------------- output head ----------------
__global__ __launch_bounds__(256) void out_kernel(const float* __restrict__ h,
                                                  const float* __restrict__ W_out,
                                                  const float* __restrict__ b_out,
                                                  float* __restrict__ out) {
    const int n = blockIdx.x * 256 + threadIdx.x;
    float a0 = 0.f, a1 = 0.f, a2 = 0.f;
    const float4* h4 = (const float4*)(h + (size_t)n*WIDTH);
#pragma unroll 4
    for (int k4 = 0; k4 < WIDTH/4; ++k4) {
        float4 v = h4[k4]; int k = k4*4;
        a0 = fmaf(v.x, W_out[(k+0)*3+0], a0); a1 = fmaf(v.x, W_out[(k+0)*3+1], a1); a2 = fmaf(v.x, W_out[(k+0)*3+2], a2);
        a0 = fmaf(v.y, W_out[(k+1)*3+0], a0); a1 = fmaf(v.y, W_out[(k+1)*3+1], a1); a2 = fmaf(v.y, W_out[(k+1)*3+2], a2);
        a0 = fmaf(v.z, W_out[(k+2)*3+0], a0); a1 = fmaf(v.z, W_out[(k+2)*3+1], a1); a2 = fmaf(v.z, W_out[(k+2)*3+2], a2);
        a0 = fmaf(v.w, W_out[(k+3)*3+0], a0); a1 = fmaf(v.w, W_out[(k+3)*3+1], a1); a2 = fmaf(v.w, W_out[(k+3)*3+2], a2);
    }
    out[n*3+0] = (a0 + b_out[0]) * 0.01f;
    out[n*3+1] = (a1 + b_out[1]) * 0.01f;
    out[n*3+2] = (a2 + b_out[2]) * 0.01f;
}

extern "C" void kernel_launch(void* const* d_in, const int* in_sizes, int n_in,
                              void* d_out, int out_size, void* d_ws, size_t ws_size,
                              hipStream_t stream) {
    const float* x      = (const float*)d_in[0];
    const float* cond   = (const float*)d_in[1];
    const float* Bf     = (const float*)d_in[2];
    const float* W_in   = (const float*)d_in[3];
    const float* b_in   = (const float*)d_in[4];
    const float* Wg_in  = (const float*)d_in[5];
    const float* bg_in  = (const float*)d_in[6];
    const float* Ws     = (const float*)d_in[7];
    const float* Wn     = (const float*)d_in[8];
    const float* bg     = (const float*)d_in[9];
    const float* Wg_out = (const float*)d_in[10];
    const float* W      = (const float*)d_in[11];
    const float* bmlp   = (const float*)d_in[12];
    const float* Wf_g   = (const float*)d_in[13];
    const float* bf_g   = (const float*)d_in[14];
    const float* Wf_b   = (const float*)d_in[15];
    const float* bf_b   = (const float*)d_in[16];
    const float* W_out  = (const float*)d_in[17];
    const float* b_out  = (const float*)d_in[18];
    float* out = (float*)d_out;

    char* ws = (char*)d_ws;
    int*    knn_idx = (int*)   (ws + 0);          //  3,145,728
    float4* xw      = (float4*)(ws + 3145728);    //  1,048,576 (dead after knn_part)
    float*  film    = (float*) (ws + 4194304);    //     14,336
    float*  h0      = (float*) (ws + 4456448);    // 67,108,864
    // pd/pi overlay h0's region: dead before fourier_input_kernel writes h0
    float*  pd      = (float*) (ws + 4456448);                 // 12,582,912
    int*    pi      = (int*)   (ws + 4456448 + 12582912);      // 12,582,912
    float*  g_a     = (float*) (ws + 71565312);   // 50,331,648
    float*  g_b     = (float*) (ws + 121896960);  // 50,331,648
    float*  agg     = (float*) (ws + 172228608);  // 50,331,648
    float*  hA      = (float*) (ws + 121896960);  // overlays g_b+agg (dead at inject)
    float*  hB      = (float*) (ws + 189005824);  // ends 256,114,688

    prep_xw_kernel<<<NN/256, 256, 0, stream>>>(x, xw);
    knn_part_kernel<<<dim3(NN/256, KSEG), 256, 0, stream>>>(xw, pd, pi);
    knn_merge_kernel<<<NN/256, 256, 0, stream>>>(pd, pi, knn_idx);
    film_kernel<<<DEPTH, 256, 0, stream>>>(cond, Wf_g, bf_g, Wf_b, bf_b, film);
    fourier_input_kernel<<<NN/256, 256, 0, stream>>>(x, Bf, W_in, b_in, Wg_in, bg_in, h0, g_a);

    float* gin = g_a; float* gout = g_b;
    for (int l = 0; l < GLAYERS; ++l) {
        gather_mean_kernel<<<NN, GW, 0, stream>>>(gin, knn_idx, agg);
        gemm64<0><<<dim3(M64, GW/64), 256, 0, stream>>>(
            gin, agg, Ws + (size_t)l*GW*GW, Wn + (size_t)l*GW*GW,
            GW, GW, GW, bg + l*GW, nullptr, nullptr, gout, 0);
        float* t = gin; gin = gout; gout = t;
    }
    gemm64<2><<<dim3(M64, WIDTH/64), 256, 0, stream>>>(
        gin, nullptr, Wg_out, nullptr, GW, 0, WIDTH, nullptr, nullptr, h0, hA, 0);

    float* hin = hA; float* hout = hB;
    for (int l = 0; l < DEPTH; ++l) {
        int skip = (l == 2 || l == 5) ? 1 : 0;
        gemm64<1><<<dim3(M64, WIDTH/64), 256, 0, stream>>>(
            hin, nullptr, W + (size_t)l*WIDTH*WIDTH, nullptr,
            WIDTH, 0, WIDTH, bmlp + l*WIDTH, film + l*2*WIDTH, h0, hout, skip);
        float* t = hin; hin = hout; hout = t;
    }
    out_kernel<<<NN/256, 256, 0, stream>>>(hin, W_out, b_out, out);
}

// Round 4
// 2590.227 us; speedup vs baseline: 3.3965x; 1.6429x over previous
//
#include <hip/hip_runtime.h>
#include <math.h>

#define NN      65536
#define KNN     12
#define WIDTH   256
#define GW      192
#define DEPTH   7
#define GLAYERS 4
#define FF      48

#define KSEG    4            // knn split-K segments
#define SEGLEN  (NN/KSEG)    // 16384 candidates per segment
#define TILE    512          // LDS candidate tile (float4) = 8 KB
#define QCAP    16           // per-lane deferral queue capacity (32 KB)
#define QTRIG   8            // flush when any lane count >= QTRIG (batch adds <=8)

typedef __attribute__((ext_vector_type(8))) _Float16 half8;
typedef __attribute__((ext_vector_type(4))) _Float16 half4;
typedef __attribute__((ext_vector_type(4))) float    f4;

__device__ __forceinline__ float silu_f(float v) { return v / (1.0f + expf(-v)); }

// ---------------- prep: pack x + |x|^2 as float4 ----------------
__global__ __launch_bounds__(256) void prep_xw_kernel(const float* __restrict__ x,
                                                      float4* __restrict__ xw) {
    int i = blockIdx.x * 256 + threadIdx.x;
    float a = x[3*i], b = x[3*i+1], c = x[3*i+2];
    xw[i] = make_float4(a, b, c, a*a + b*b + c*c);
}

// ---------------- kNN split-K scan with per-lane LDS deferral queue ----------------
__device__ __forceinline__ void knn_flush(float2* qbuf, int tid, int& cnt,
                                          float bd[KNN], int bi[KNN], float& worst) {
    int p = 0;
    while (__any(p < cnt)) {
        if (p < cnt) {
            float2 e = qbuf[p*256 + tid];
            float d = e.x;
            if (d < bd[KNN-1]) {
                bd[KNN-1] = d; bi[KNN-1] = __float_as_int(e.y);
#pragma unroll
                for (int k = KNN-1; k > 0; --k) {
                    if (bd[k] < bd[k-1]) {
                        float td = bd[k]; bd[k] = bd[k-1]; bd[k-1] = td;
                        int   ti = bi[k]; bi[k] = bi[k-1]; bi[k-1] = ti;
                    }
                }
            }
        }
        ++p;
    }
    cnt = 0;
    worst = bd[KNN-1];
}

__global__ __launch_bounds__(256) void knn_part_kernel(const float4* __restrict__ xw,
                                                       float* __restrict__ pd,
                                                       int* __restrict__ pi) {
    __shared__ float4 tile[TILE];
    __shared__ float2 qbuf[QCAP*256];
    const int tid = threadIdx.x;
    const int q   = blockIdx.x * 256 + tid;
    const int seg = blockIdx.y;
    const float4 me = xw[q];
    const float qsq = me.w;
    float bd[KNN]; int bi[KNN];
#pragma unroll
    for (int k = 0; k < KNN; ++k) { bd[k] = 3e38f; bi[k] = -1; }
    float worst = 3e38f;
    int cnt = 0;

    for (int t0 = seg*SEGLEN; t0 < (seg+1)*SEGLEN; t0 += TILE) {
        __syncthreads();
        tile[tid]       = xw[t0 + tid];
        tile[tid + 256] = xw[t0 + 256 + tid];
        __syncthreads();
        for (int b = 0; b < TILE; b += 8) {
            if (__any(cnt >= QTRIG)) knn_flush(qbuf, tid, cnt, bd, bi, worst);
            float d[8];
#pragma unroll
            for (int u = 0; u < 8; ++u) {
                float4 c = tile[b + u];
                float dot = me.x*c.x + me.y*c.y + me.z*c.z;
                d[u] = fmaf(-2.0f, dot, qsq + c.w);
            }
            float m01 = fminf(d[0],d[1]), m23 = fminf(d[2],d[3]);
            float m45 = fminf(d[4],d[5]), m67 = fminf(d[6],d[7]);
            float mn = fminf(fminf(m01,m23), fminf(m45,m67));
            if (mn < worst) {
#pragma unroll
                for (int u = 0; u < 8; ++u) {
                    if (d[u] < worst) {
                        int gj = t0 + b + u;
                        if (gj != q) {
                            float dc = fmaxf(d[u], 0.0f);
                            qbuf[cnt*256 + tid] = make_float2(dc, __int_as_float(gj));
                            ++cnt;
                        }
                    }
                }
            }
        }
    }
    knn_flush(qbuf, tid, cnt, bd, bi, worst);
#pragma unroll
    for (int k = 0; k < KNN; ++k) {
        pd[(q*KSEG + seg)*KNN + k] = bd[k];
        pi[(q*KSEG + seg)*KNN + k] = bi[k];
    }
}

__global__ __launch_bounds__(256) void knn_merge_kernel(const float* __restrict__ pd,
                                                        const int* __restrict__ pi,
                                                        int* __restrict__ knn_idx) {
    const int q = blockIdx.x * 256 + threadIdx.x;
    float bd[KNN]; int bi[KNN];
#pragma unroll
    for (int k = 0; k < KNN; ++k) { bd[k] = pd[q*KSEG*KNN + k]; bi[k] = pi[q*KSEG*KNN + k]; }
#pragma unroll
    for (int s = 1; s < KSEG; ++s) {
        for (int k = 0; k < KNN; ++k) {
            float d = pd[(q*KSEG + s)*KNN + k];
            if (d >= bd[KNN-1]) break;
            int gi = pi[(q*KSEG + s)*KNN + k];
            bd[KNN-1] = d; bi[KNN-1] = gi;
#pragma unroll
            for (int t = KNN-1; t > 0; --t) {
                if (bd[t] < bd[t-1]) {
                    float td = bd[t]; bd[t] = bd[t-1]; bd[t-1] = td;
                    int   ti = bi[t]; bi[t] = bi[t-1]; bi[t-1] = ti;
                }
            }
        }
    }
#pragma unroll
    for (int k = 0; k < KNN; ++k) knn_idx[q*KNN + k] = bi[k];
}

// ---------------- weight convert+transpose to f16 [N][K] ----------------
__global__ __launch_bounds__(256) void convert_Wt_kernel(const float* __restrict__ W,
                                                         _Float16* __restrict__ Wt) {
    int e = blockIdx.x*256 + threadIdx.x;          // over DEPTH*65536
    int l = e >> 16, r = e & 65535;
    int n = r >> 8, k = r & 255;
    Wt[(size_t)l*65536 + n*256 + k] = (_Float16)W[(size_t)l*65536 + k*256 + n];
}

__global__ __launch_bounds__(256) void convert_Bg_kernel(const float* __restrict__ Ws,
                                                         const float* __restrict__ Wn,
                                                         _Float16* __restrict__ Bg) {
    int e = blockIdx.x*256 + threadIdx.x;          // over GLAYERS*192*384
    int l = e / 73728, r = e % 73728;
    int n = r / 384, k = r % 384;
    float v = (k < 192) ? Ws[(size_t)l*36864 + k*192 + n]
                        : Wn[(size_t)l*36864 + (k-192)*192 + n];
    Bg[(size_t)l*73728 + (size_t)n*384 + k] = (_Float16)v;
}

__global__ __launch_bounds__(256) void convert_Wgo_kernel(const float* __restrict__ Wg_out,
                                                          _Float16* __restrict__ Wgo) {
    int e = blockIdx.x*256 + threadIdx.x;          // over 256*192
    int n = e / 192, k = e % 192;
    Wgo[e] = (_Float16)Wg_out[k*256 + n];
}

// ---------------- fourier features + both input layers (f16 out) ----------------
__global__ __launch_bounds__(256) void fourier_input_kernel(
    const float* __restrict__ x, const float* __restrict__ Bf,
    const float* __restrict__ W_in, const float* __restrict__ b_in,
    const float* __restrict__ Wg_in, const float* __restrict__ bg_in,
    _Float16* __restrict__ h0, _Float16* __restrict__ g0) {
    const int n = blockIdx.x * 256 + threadIdx.x;
    const float x0 = x[3*n], x1 = x[3*n+1], x2 = x[3*n+2];
    float ff[FF];
#pragma unroll
    for (int sm = 0; sm < 24; ++sm) {
        int s = sm >> 3, m = sm & 7;
        float p = x0*Bf[s*24 + m] + x1*Bf[s*24 + 8 + m] + x2*Bf[s*24 + 16 + m];
        float sv, cv; sincosf(p, &sv, &cv);
        ff[sm] = sv; ff[24 + sm] = cv;
    }
    {
        const float4* W4 = (const float4*)W_in;
        const float4* b4 = (const float4*)b_in;
#pragma unroll 2
        for (int j4 = 0; j4 < WIDTH/4; ++j4) {
            float4 acc = b4[j4];
#pragma unroll
            for (int k = 0; k < FF; ++k) {
                float4 w = W4[k*(WIDTH/4) + j4]; float f = ff[k];
                acc.x = fmaf(f, w.x, acc.x); acc.y = fmaf(f, w.y, acc.y);
                acc.z = fmaf(f, w.z, acc.z); acc.w = fmaf(f, w.w, acc.w);
            }
            half4 o;
            o[0] = (_Float16)silu_f(acc.x); o[1] = (_Float16)silu_f(acc.y);
            o[2] = (_Float16)silu_f(acc.z); o[3] = (_Float16)silu_f(acc.w);
            *(half4*)&h0[(size_t)n*WIDTH + j4*4] = o;
        }
    }
    {
        const float4* W4 = (const float4*)Wg_in;
        const float4* b4 = (const float4*)bg_in;
#pragma unroll 2
        for (int j4 = 0; j4 < GW/4; ++j4) {
            float4 acc = b4[j4];
#pragma unroll
            for (int k = 0; k < FF; ++k) {
                float4 w = W4[k*(GW/4) + j4]; float f = ff[k];
                acc.x = fmaf(f, w.x, acc.x); acc.y = fmaf(f, w.y, acc.y);
                acc.z = fmaf(f, w.z, acc.z); acc.w = fmaf(f, w.w, acc.w);
            }
            half4 o;
            o[0] = (_Float16)silu_f(acc.x); o[1] = (_Float16)silu_f(acc.y);
            o[2] = (_Float16)silu_f(acc.z); o[3] = (_Float16)silu_f(acc.w);
            *(half4*)&g0[(size_t)n*GW + j4*4] = o;
        }
    }
}

// ---------------- gather + mean over 12 neighbors (f16) ----------------
__global__ __launch_bounds__(192) void gather_mean_kernel(const _Float16* __restrict__ g,
                                                          const int* __restrict__ idx,
                                                          _Float16* __restrict__ agg) {
    __shared__ int nb[KNN];
    const int n = blockIdx.x;
    if (threadIdx.x < KNN) nb[threadIdx.x] = idx[n*KNN + threadIdx.x];
    __syncthreads();
    float acc = 0.0f;
#pragma unroll
    for (int k = 0; k < KNN; ++k) acc += (float)g[(size_t)nb[k]*GW + threadIdx.x];
    agg[(size_t)n*GW + threadIdx.x] = (_Float16)(acc * (1.0f/12.0f));
}

// ---------------- FiLM params ----------------
__global__ __launch_bounds__(256) void film_kernel(const float* __restrict__ cond,
                                                   const float* __restrict__ Wf_g,
                                                   const float* __restrict__ bf_g,
                                                   const float* __restrict__ Wf_b,
                                                   const float* __restrict__ bf_b,
                                                   float* __restrict__ film) {
    const int l = blockIdx.x, j = threadIdx.x;
    float g = bf_g[l*WIDTH + j], b = bf_b[l*WIDTH + j];
    for (int c = 0; c < 64; ++c) {
        float cv = cond[c];
        g = fmaf(cv, Wf_g[(size_t)(l*64 + c)*WIDTH + j], g);
        b = fmaf(cv, Wf_b[(size_t)(l*64 + c)*WIDTH + j], b);
    }
    film[l*2*WIDTH + j]         = 1.0f + g;
    film[l*2*WIDTH + WIDTH + j] = b;
}

// ---------------- f16 MFMA GEMM: BM=128, BN=64, 4 waves ----------------
// A row-major f16 (concat A1|A2 along k), Bt = B^T row-major [NC][Ktot] f16.
// EPI: 0 silu(acc+bias); 1 silu((acc+bias)*fg+fb)[+h0]; 2 acc+h0.
template<int EPI>
__global__ __launch_bounds__(256) void gemm_mfma(
    const _Float16* __restrict__ A1, const _Float16* __restrict__ A2,
    const _Float16* __restrict__ Bt, int K1, int Ktot, int NC,
    const float* __restrict__ bias, const float* __restrict__ film,
    const _Float16* __restrict__ h0, _Float16* __restrict__ C, int addSkip) {
    __shared__ _Float16 As[128*40];   // stride 40 f16 = 80 B: 16B-aligned rows
    __shared__ _Float16 Bs[64*40];
    const int tid = threadIdx.x;
    const int bm = blockIdx.x * 128, bn = blockIdx.y * 64;
    const int wid = tid >> 6, lane = tid & 63;
    const int wm = (wid & 1) * 64, wn = (wid >> 1) * 32;
    const int m16 = lane & 15, kq = lane >> 4;
    const int ar = tid >> 1, ah = tid & 1;     // A: 128 rows x 2 k-halves of 16 f16 (=2 float4)
    const int br = tid >> 2, bq = tid & 3;     // B: 64 rows x 4 k-quarters of 8 f16 (=1 float4)
    f4 acc[4][2];
#pragma unroll
    for (int i = 0; i < 4; ++i)
#pragma unroll
        for (int j = 0; j < 2; ++j) acc[i][j] = (f4){0.f, 0.f, 0.f, 0.f};

    for (int kc = 0; kc < Ktot; kc += 32) {
        const _Float16* Asrc; int kl, ldA;
        if (kc < K1) { Asrc = A1; kl = kc;      ldA = K1; }
        else         { Asrc = A2; kl = kc - K1; ldA = Ktot - K1; }
        {   // stage 16 f16 (32 B) per thread: full 128x32 A tile
            const float4* src = (const float4*)&Asrc[(size_t)(bm + ar)*ldA + kl + ah*16];
            *(float4*)&As[ar*40 + ah*16]     = src[0];
            *(float4*)&As[ar*40 + ah*16 + 8] = src[1];
        }
        *(float4*)&Bs[br*40 + bq*8] = *(const float4*)&Bt[(size_t)(bn + br)*Ktot + kc + bq*8];
        __syncthreads();
        half8 af[4], bf[2];
#pragma unroll
        for (int mt = 0; mt < 4; ++mt) af[mt] = *(half8*)&As[(wm + mt*16 + m16)*40 + kq*8];
#pragma unroll
        for (int nt = 0; nt < 2; ++nt) bf[nt] = *(half8*)&Bs[(wn + nt*16 + m16)*40 + kq*8];
#pragma unroll
        for (int mt = 0; mt < 4; ++mt)
#pragma unroll
            for (int nt = 0; nt < 2; ++nt)
                acc[mt][nt] = __builtin_amdgcn_mfma_f32_16x16x32_f16(af[mt], bf[nt], acc[mt][nt], 0, 0, 0);
        __syncthreads();
    }

#pragma unroll
    for (int mt = 0; mt < 4; ++mt) {
#pragma unroll
        for (int nt = 0; nt < 2; ++nt) {
            int col = bn + wn + nt*16 + m16;
#pragma unroll
            for (int r = 0; r < 4; ++r) {
                int row = bm + wm + mt*16 + kq*4 + r;   // C/D: col=lane&15, row=quad*4+reg
                float v = acc[mt][nt][r];
                if (EPI == 0) {
                    v = silu_f(v + bias[col]);
                } else if (EPI == 1) {
                    v = fmaf(v + bias[col], film[col], film[NC + col]);
                    v = silu_f(v);
                    if (addSkip) v += (float)h0[(size_t)row*NC + col];
                } else {
                    v += (float)h0[(size_t)row*NC + col];
                }
                C[(size_t)row*NC + col] = (_Float16)v;
            }
        }
    }
}

// ---------------- output head: (h @ W_out + b_out) * 0.01 ----------------
__global__ __launch_bounds__(256) void out_kernel(const _Float16* __restrict__ h,
                                                  const float* __restrict__ W_out,
                                                  const float* __restrict__ b_out,
                                                  float* __restrict__ out) {
    const int n = blockIdx.x * 256 + threadIdx.x;
    float a0 = 0.f, a1 = 0.f, a2 = 0.f;
#pragma unroll 4
    for (int k8 = 0; k8 < WIDTH/8; ++k8) {
        half8 v = *(const half8*)&h[(size_t)n*WIDTH + k8*8];
#pragma unroll
        for (int u = 0; u < 8; ++u) {
            float f = (float)v[u]; int k = k8*8 + u;
            a0 = fmaf(f, W_out[k*3+0], a0);
            a1 = fmaf(f, W_out[k*3+1], a1);
            a2 = fmaf(f, W_out[k*3+2], a2);
        }
    }
    out[n*3+0] = (a0 + b_out[0]) * 0.01f;
    out[n*3+1] = (a1 + b_out[1]) * 0.01f;
    out[n*3+2] = (a2 + b_out[2]) * 0.01f;
}

extern "C" void kernel_launch(void* const* d_in, const int* in_sizes, int n_in,
                              void* d_out, int out_size, void* d_ws, size_t ws_size,
                              hipStream_t stream) {
    const float* x      = (const float*)d_in[0];
    const float* cond   = (const float*)d_in[1];
    const float* Bf     = (const float*)d_in[2];
    const float* W_in   = (const float*)d_in[3];
    const float* b_in   = (const float*)d_in[4];
    const float* Wg_in  = (const float*)d_in[5];
    const float* bg_in  = (const float*)d_in[6];
    const float* Ws     = (const float*)d_in[7];
    const float* Wn     = (const float*)d_in[8];
    const float* bg     = (const float*)d_in[9];
    const float* Wg_out = (const float*)d_in[10];
    const float* W      = (const float*)d_in[11];
    const float* bmlp   = (const float*)d_in[12];
    const float* Wf_g   = (const float*)d_in[13];
    const float* bf_g   = (const float*)d_in[14];
    const float* Wf_b   = (const float*)d_in[15];
    const float* bf_b   = (const float*)d_in[16];
    const float* W_out  = (const float*)d_in[17];
    const float* b_out  = (const float*)d_in[18];
    float* out = (float*)d_out;

    char* ws = (char*)d_ws;
    int*       knn_idx = (int*)      (ws + 0);          //  3,145,728
    float4*    xw      = (float4*)   (ws + 3145728);    //  1,048,576
    float*     film    = (float*)    (ws + 4194304);    //     14,336
    _Float16*  Bg_t    = (_Float16*) (ws + 4210688);    //    589,824
    _Float16*  Wgo_t   = (_Float16*) (ws + 4800512);    //     98,304
    _Float16*  Wt      = (_Float16*) (ws + 4898816);    //    917,504
    _Float16*  h0      = (_Float16*) (ws + 5816320);    // 33,554,432 (f16)
    // pd/pi overlay h0 region: dead before fourier_input writes h0
    float*     pd      = (float*)    (ws + 5816320);                 // 12,582,912
    int*       pi      = (int*)      (ws + 5816320 + 12582912);      // 12,582,912
    _Float16*  g_a     = (_Float16*) (ws + 39370752);   // 25,165,824
    _Float16*  g_b     = (_Float16*) (ws + 64536576);   // 25,165,824
    _Float16*  agg     = (_Float16*) (ws + 89702400);   // 25,165,824
    _Float16*  hA      = (_Float16*) (ws + 114868224);  // 33,554,432
    _Float16*  hB      = (_Float16*) (ws + 148422656);  // 33,554,432 -> ends 181,977,088

    prep_xw_kernel<<<NN/256, 256, 0, stream>>>(x, xw);
    knn_part_kernel<<<dim3(NN/256, KSEG), 256, 0, stream>>>(xw, pd, pi);
    knn_merge_kernel<<<NN/256, 256, 0, stream>>>(pd, pi, knn_idx);
    film_kernel<<<DEPTH, 256, 0, stream>>>(cond, Wf_g, bf_g, Wf_b, bf_b, film);
    convert_Wt_kernel<<<DEPTH*65536/256, 256, 0, stream>>>(W, Wt);
    convert_Bg_kernel<<<GLAYERS*73728/256, 256, 0, stream>>>(Ws, Wn, Bg_t);
    convert_Wgo_kernel<<<256*192/256, 256, 0, stream>>>(Wg_out, Wgo_t);
    fourier_input_kernel<<<NN/256, 256, 0, stream>>>(x, Bf, W_in, b_in, Wg_in, bg_in, h0, g_a);

    _Float16* gin = g_a; _Float16* gout = g_b;
    for (int l = 0; l < GLAYERS; ++l) {
        gather_mean_kernel<<<NN, GW, 0, stream>>>(gin, knn_idx, agg);
        gemm_mfma<0><<<dim3(NN/128, GW/64), 256, 0, stream>>>(
            gin, agg, Bg_t + (size_t)l*73728, GW, 2*GW, GW,
            bg + l*GW, nullptr, nullptr, gout, 0);
        _Float16* t = gin; gin = gout; gout = t;
    }
    // gin == g_a (4 swaps). inject: hA = h0 + gin @ Wg_out
    gemm_mfma<2><<<dim3(NN/128, WIDTH/64), 256, 0, stream>>>(
        gin, nullptr, Wgo_t, GW, GW, WIDTH, nullptr, nullptr, h0, hA, 0);

    _Float16* hin = hA; _Float16* hout = hB;
    for (int l = 0; l < DEPTH; ++l) {
        int skip = (l == 2 || l == 5) ? 1 : 0;   // SKIPS=(3,6): after layers idx 2,5
        gemm_mfma<1><<<dim3(NN/128, WIDTH/64), 256, 0, stream>>>(
            hin, nullptr, Wt + (size_t)l*65536, WIDTH, WIDTH, WIDTH,
            bmlp + l*WIDTH, film + l*2*WIDTH, h0, hout, skip);
        _Float16* t = hin; hin = hout; hout = t;
    }
    out_kernel<<<NN/256, 256, 0, stream>>>(hin, W_out, b_out, out);
}